// Round 7
// baseline (212.659 us; speedup 1.0000x reference)
//
#include <hip/hip_runtime.h>
#include <math.h>

#define BATCH    65536
#define FEAT     512
#define NCLASS   16
#define LAMDA    1.0f
#define LAMDA1   10.0f
#define SCALE    1.0f
#define EPS      1e-9f

constexpr int BLOCK  = 256;
constexpr int GRID   = 4096;
constexpr int NV     = BATCH * (FEAT / 4);     // 8,388,608 float4 elements
constexpr int STRIDE = GRID * BLOCK;           // 1,048,576
constexpr int ITERS  = NV / STRIDE;            // exactly 8

// Workspace layout (float slots):
//   [0, GRID)  : per-block partial sums
//   [GRID]     : item1 (gram cosine sum), computed by block GRID of k1
constexpr int WS_ITEM1 = GRID;

typedef float f4v __attribute__((ext_vector_type(4)));

// ---------------------------------------------------------------------------
// R6 post-mortem: deep VGPR-resident asm-load pipelines are unsafe — regalloc
// may copy/spill an asm-"output" register BEFORE its load data lands (the
// compiler assumes asm outputs are ready at asm retire). 1.9e19 garbage.
// R7: test the last untried lever — the RETURN PATH. x is staged straight
// into LDS via global_load_lds (no destination VGPRs exist -> hazard class
// gone; no L1 allocate -> centers table stays hot, dodging R4's thrash).
// Each wave stages only its own 64-lane chunks -> wave-private LDS regions,
// per-wave s_waitcnt vmcnt(0), NO __syncthreads in the streaming path.
// Per-thread consumption order identical to R0/R3 -> bit-exact result.
// Pre-commit: neutral (>=200 us) => read path ~3 TB/s is the machine rate
// for this pattern; declare roofline next round.
// ---------------------------------------------------------------------------
__global__ __launch_bounds__(BLOCK) void island_main(
    const f4v* __restrict__ x,         // [BATCH * FEAT/4]
    const int* __restrict__ y,         // [BATCH]
    const f4v* __restrict__ centers4,  // [NCLASS * FEAT/4]
    float*     __restrict__ ws)        // see layout above
{
    __shared__ float wsum[4];
    __shared__ float gram[NCLASS][NCLASS];
    __shared__ f4v   xstage[ITERS * BLOCK];    // 8 * 256 * 16B = 32 KiB

    const int bid  = blockIdx.x;
    const int t    = threadIdx.x;
    const int lane = t & 63;
    const int wid  = t >> 6;

    if (bid < GRID) {
        // ---------------- center-loss streaming path ----------------------
        const int tid = bid * BLOCK + t;

        // wave-uniform sample-row base -> y loads become s_loads.
        const int base_b = __builtin_amdgcn_readfirstlane(tid >> 7);
        const int d4     = t & 127;            // == tid & 127 (BLOCK==256)

        int cls[ITERS];
        #pragma unroll
        for (int it = 0; it < ITERS; ++it)
            cls[it] = y[base_b + it * (STRIDE >> 7)];

        // Issue 8 direct-to-LDS loads. HW semantics (m104): LDS dest =
        // wave-uniform base + lane*16B; global src is per-lane. Wave wid's
        // region for iter it starts at element it*BLOCK + wid*64, so thread
        // t's data lands at xstage[it*BLOCK + t]. Zero data VGPRs consumed.
        #pragma unroll
        for (int it = 0; it < ITERS; ++it) {
            const f4v* g = &x[tid + it * STRIDE];
            f4v*       l = &xstage[it * BLOCK + wid * 64];
            __builtin_amdgcn_global_load_lds(
                (const __attribute__((address_space(1))) void*)g,
                (__attribute__((address_space(3))) void*)l,
                16, 0, 0);
        }
        // Per-wave drain; each wave reads only its own staged chunks, so no
        // barrier is needed. "memory" clobber orders the ds_reads after it.
        asm volatile("s_waitcnt vmcnt(0)" ::: "memory");

        float sum = 0.0f;
        #pragma unroll
        for (int it = 0; it < ITERS; ++it) {
            f4v xv = xstage[it * BLOCK + t];                 // ds_read_b128
            f4v cv = centers4[cls[it] * (FEAT / 4) + d4];    // L1-hot table
            f4v e  = xv - cv;
            sum += e.x * e.x + e.y * e.y + e.z * e.z + e.w * e.w;
        }

        #pragma unroll
        for (int off = 32; off > 0; off >>= 1)
            sum += __shfl_down(sum, off, 64);

        if (lane == 0) wsum[wid] = sum;
        __syncthreads();
        if (t == 0)
            ws[bid] = wsum[0] + wsum[1] + wsum[2] + wsum[3];
    } else {
        // ---------------- gram + item1 (hidden under the stream) ----------
        const int j = t >> 4;
        const int k = t & 15;
        const f4v* cj = centers4 + j * (FEAT / 4);
        const f4v* ck = centers4 + k * (FEAT / 4);
        float dot = 0.0f;
        #pragma unroll 8
        for (int i = 0; i < FEAT / 4; ++i) {
            f4v a = cj[i];
            f4v b = ck[i];
            dot += a.x * b.x + a.y * b.y + a.z * b.z + a.w * b.w;
        }
        gram[j][k] = dot;
        __syncthreads();

        if (t == 0) {
            // EXACT old-finalize item1 arithmetic/order.
            float item1 = 0.0f;
            for (int jj = 0; jj < NCLASS; ++jj) {
                float nj = sqrtf(gram[jj][jj]);
                for (int kk = jj + 1; kk < NCLASS; ++kk) {
                    float nk = sqrtf(gram[kk][kk]);
                    item1 += gram[jj][kk] / (nj * nk + EPS) + 1.0f;
                }
            }
            ws[WS_ITEM1] = item1;
        }
    }
}

// ---------------------------------------------------------------------------
// Kernel 2 (single block): bare 4096-partial reduce + combine. ~2-3 us.
// Same reduction order as all previous rounds -> bit-identical result.
// ---------------------------------------------------------------------------
__global__ __launch_bounds__(256) void finalize_kernel(
    const float* __restrict__ ws,   // partials [GRID] + item1 at [WS_ITEM1]
    float*       __restrict__ out)  // [1]
{
    float psum = 0.0f;
    #pragma unroll
    for (int k = 0; k < GRID / 256; ++k)
        psum += ws[threadIdx.x + k * 256];
    #pragma unroll
    for (int off = 32; off > 0; off >>= 1)
        psum += __shfl_down(psum, off, 64);

    __shared__ float wsum[4];
    const int lane = threadIdx.x & 63;
    const int wid  = threadIdx.x >> 6;
    if (lane == 0) wsum[wid] = psum;
    __syncthreads();

    if (threadIdx.x == 0) {
        float total = wsum[0] + wsum[1] + wsum[2] + wsum[3];
        float loss_center = 0.5f * total * (SCALE / (float)BATCH);
        out[0] = LAMDA * (loss_center + LAMDA1 * ws[WS_ITEM1]);
    }
}

extern "C" void kernel_launch(void* const* d_in, const int* in_sizes, int n_in,
                              void* d_out, int out_size, void* d_ws, size_t ws_size,
                              hipStream_t stream) {
    const float* x       = (const float*)d_in[0];   // [BATCH, FEAT]
    const int*   y       = (const int*)d_in[1];     // [BATCH]
    const float* centers = (const float*)d_in[2];   // [NCLASS, FEAT]
    float* out = (float*)d_out;
    float* ws  = (float*)d_ws;

    island_main<<<GRID + 1, BLOCK, 0, stream>>>(
        (const f4v*)x, y, (const f4v*)centers, ws);

    finalize_kernel<<<1, 256, 0, stream>>>(ws, out);
}

// Round 8
// 199.463 us; speedup vs baseline: 1.0662x; 1.0662x over previous
//
#include <hip/hip_runtime.h>
#include <math.h>

#define BATCH    65536
#define FEAT     512
#define NCLASS   16
#define LAMDA    1.0f
#define LAMDA1   10.0f
#define SCALE    1.0f
#define EPS      1e-9f

constexpr int BLOCK  = 256;
constexpr int OGRID  = 4096;               // logical grid (partials layout, bit-exact)
constexpr int PAIR   = 2;                  // logical blocks per physical block
constexpr int GRID2  = OGRID / PAIR;       // 2048 physical streaming blocks
constexpr int NV     = BATCH * (FEAT / 4); // 8,388,608 float4 elements
constexpr int STRIDE = OGRID * BLOCK;      // 1,048,576 — UNCHANGED element mapping
constexpr int ITERS  = NV / STRIDE;        // 8 per logical block — UNCHANGED

// Workspace layout (float slots):
//   [0, OGRID)  : per-logical-block partial sums (same 4096 slots as always)
//   [OGRID]     : item1 (gram cosine sum)
constexpr int WS_ITEM1 = OGRID;

typedef float f4v __attribute__((ext_vector_type(4)));

// ---------------------------------------------------------------------------
// R7 lesson: LDS return path slightly worse; all three per-wave memory paths
// land at 46-56 us -> per-wave mechanics exonerated. Occupancy arithmetic
// (23% => ~1.8 blocks/CU resident, no resource limit) + R3's warm replays
// (80 us at ZERO HBM fetch: duration independent of memory source) point at
// BLOCK CHURN/residency: 4096 short-lived blocks, each one memory-latency
// lifetime, too few co-resident. R8 tests that axis safely: 2048 blocks x
// 2 logical blocks each, straight-line (no barrier between the halves), with
// compiler-scheduled nt loads exactly as R3 (best-known per-wave config).
// Per-logical-block arithmetic/order/layout identical -> bit-exact.
// ---------------------------------------------------------------------------
__global__ __launch_bounds__(BLOCK) void island_main(
    const f4v* __restrict__ x,         // [BATCH * FEAT/4]
    const int* __restrict__ y,         // [BATCH]
    const f4v* __restrict__ centers4,  // [NCLASS * FEAT/4]
    float*     __restrict__ ws)        // see layout above
{
    __shared__ float wsum[4];
    __shared__ float gram[NCLASS][NCLASS];

    const int bid  = blockIdx.x;
    const int t    = threadIdx.x;
    const int lane = t & 63;
    const int wid  = t >> 6;

    if (bid < GRID2) {
        // ---------------- two logical blocks, straight-line ---------------
        const int d4 = t & 127;
        float sums[PAIR];

        #pragma unroll
        for (int p = 0; p < PAIR; ++p) {
            const int lb  = bid + p * GRID2;       // logical block id
            const int tid = lb * BLOCK + t;

            // wave-uniform sample-row base -> y loads become s_loads.
            const int base_b = __builtin_amdgcn_readfirstlane(tid >> 7);

            int cls[ITERS];
            #pragma unroll
            for (int it = 0; it < ITERS; ++it)
                cls[it] = y[base_b + it * (STRIDE >> 7)];

            float sum = 0.0f;
            #pragma unroll
            for (int it = 0; it < ITERS; ++it) {
                // nt on the x stream (R4: plain loads thrash L1/L2 and evict
                // the centers table). Compiler schedules the 8 loads.
                f4v xv = __builtin_nontemporal_load(&x[tid + it * STRIDE]);
                f4v cv = centers4[cls[it] * (FEAT / 4) + d4];
                f4v e  = xv - cv;
                sum += e.x * e.x + e.y * e.y + e.z * e.z + e.w * e.w;
            }
            sums[p] = sum;
        }

        // ---------------- reductions (exact original tree/order) ----------
        #pragma unroll
        for (int p = 0; p < PAIR; ++p) {
            float sum = sums[p];
            #pragma unroll
            for (int off = 32; off > 0; off >>= 1)
                sum += __shfl_down(sum, off, 64);
            if (lane == 0) wsum[wid] = sum;
            __syncthreads();
            if (t == 0)
                ws[bid + p * GRID2] = wsum[0] + wsum[1] + wsum[2] + wsum[3];
            __syncthreads();   // wsum reuse (write-after-read)
        }
    } else {
        // ---------------- gram + item1 (hidden under the stream) ----------
        const int j = t >> 4;
        const int k = t & 15;
        const f4v* cj = centers4 + j * (FEAT / 4);
        const f4v* ck = centers4 + k * (FEAT / 4);
        float dot = 0.0f;
        #pragma unroll 8
        for (int i = 0; i < FEAT / 4; ++i) {
            f4v a = cj[i];
            f4v b = ck[i];
            dot += a.x * b.x + a.y * b.y + a.z * b.z + a.w * b.w;
        }
        gram[j][k] = dot;
        __syncthreads();

        if (t == 0) {
            // EXACT old-finalize item1 arithmetic/order.
            float item1 = 0.0f;
            for (int jj = 0; jj < NCLASS; ++jj) {
                float nj = sqrtf(gram[jj][jj]);
                for (int kk = jj + 1; kk < NCLASS; ++kk) {
                    float nk = sqrtf(gram[kk][kk]);
                    item1 += gram[jj][kk] / (nj * nk + EPS) + 1.0f;
                }
            }
            ws[WS_ITEM1] = item1;
        }
    }
}

// ---------------------------------------------------------------------------
// Kernel 2 (single block): bare 4096-partial reduce + combine. ~2-3 us.
// Same reduction order as all previous rounds -> bit-identical result.
// ---------------------------------------------------------------------------
__global__ __launch_bounds__(256) void finalize_kernel(
    const float* __restrict__ ws,   // partials [OGRID] + item1 at [WS_ITEM1]
    float*       __restrict__ out)  // [1]
{
    float psum = 0.0f;
    #pragma unroll
    for (int k = 0; k < OGRID / 256; ++k)
        psum += ws[threadIdx.x + k * 256];
    #pragma unroll
    for (int off = 32; off > 0; off >>= 1)
        psum += __shfl_down(psum, off, 64);

    __shared__ float wsum[4];
    const int lane = threadIdx.x & 63;
    const int wid  = threadIdx.x >> 6;
    if (lane == 0) wsum[wid] = psum;
    __syncthreads();

    if (threadIdx.x == 0) {
        float total = wsum[0] + wsum[1] + wsum[2] + wsum[3];
        float loss_center = 0.5f * total * (SCALE / (float)BATCH);
        out[0] = LAMDA * (loss_center + LAMDA1 * ws[WS_ITEM1]);
    }
}

extern "C" void kernel_launch(void* const* d_in, const int* in_sizes, int n_in,
                              void* d_out, int out_size, void* d_ws, size_t ws_size,
                              hipStream_t stream) {
    const float* x       = (const float*)d_in[0];   // [BATCH, FEAT]
    const int*   y       = (const int*)d_in[1];     // [BATCH]
    const float* centers = (const float*)d_in[2];   // [NCLASS, FEAT]
    float* out = (float*)d_out;
    float* ws  = (float*)d_ws;

    island_main<<<GRID2 + 1, BLOCK, 0, stream>>>(
        (const f4v*)x, y, (const f4v*)centers, ws);

    finalize_kernel<<<1, 256, 0, stream>>>(ws, out);
}